// Round 6
// baseline (3686.685 us; speedup 1.0000x reference)
//
#include <hip/hip_runtime.h>
#include <cstdint>
#include <cstddef>

#define D 256
#define H 8
#define DFF 1024

typedef short s16x8 __attribute__((ext_vector_type(8)));
typedef float f32x4 __attribute__((ext_vector_type(4)));
typedef float f32x2 __attribute__((ext_vector_type(2)));

static inline int cdiv(int a, int b) { return (a + b - 1) / b; }

__device__ inline uint16_t f2bf(float x) {
    unsigned u = __float_as_uint(x);
    u += 0x7FFFu + ((u >> 16) & 1u);
    return (uint16_t)(u >> 16);
}
__device__ inline float bf2f(uint16_t h) {
    return __uint_as_float(((unsigned)h) << 16);
}
__device__ inline uint8_t f2fp8(float x) {
    int pk = __builtin_amdgcn_cvt_pk_fp8_f32(x, x, 0, false);
    return (uint8_t)(pk & 0xFF);
}

__device__ inline void gload_lds16(const void* g, void* l) {
    __builtin_amdgcn_global_load_lds(
        (const __attribute__((address_space(1))) void*)g,
        (__attribute__((address_space(3))) void*)l, 16, 0, 0);
}

// ---------------------------------------------------------------------------
// CSR build (graph constant across layers)
// ---------------------------------------------------------------------------
__global__ __launch_bounds__(256) void zero_int_kernel(int* __restrict__ p, int count)
{
    int i = blockIdx.x * blockDim.x + threadIdx.x;
    if (i < count) p[i] = 0;
}

__global__ __launch_bounds__(256) void count_deg_kernel(
    const int* __restrict__ edst, int* __restrict__ deg, int E)
{
    int e = blockIdx.x * blockDim.x + threadIdx.x;
    if (e < E) atomicAdd(&deg[edst[e]], 1);
}

__global__ __launch_bounds__(256) void block_sum_kernel(
    const int* __restrict__ deg, int* __restrict__ bsum, int N)
{
    int t = threadIdx.x;
    int gid = blockIdx.x * 256 + t;
    int val = (gid < N) ? deg[gid] : 0;
    #pragma unroll
    for (int o = 1; o < 64; o <<= 1) val += __shfl_xor(val, o);
    __shared__ int r[4];
    if ((t & 63) == 0) r[t >> 6] = val;
    __syncthreads();
    if (t == 0) bsum[blockIdx.x] = r[0] + r[1] + r[2] + r[3];
}

__global__ __launch_bounds__(256) void scan_bsum_kernel(int* __restrict__ bsum, int nb)
{
    __shared__ int tmp[256];
    int t = threadIdx.x;
    int val = (t < nb) ? bsum[t] : 0;
    tmp[t] = val;
    __syncthreads();
    for (int off = 1; off < 256; off <<= 1) {
        int add = (t >= off) ? tmp[t - off] : 0;
        __syncthreads();
        tmp[t] += add;
        __syncthreads();
    }
    if (t < nb) bsum[t] = tmp[t] - val;
}

__global__ __launch_bounds__(256) void scan_write_kernel(
    const int* __restrict__ deg, const int* __restrict__ bsum,
    int* __restrict__ rowptr, int* __restrict__ cursor, int N)
{
    __shared__ int tmp[256];
    int t = threadIdx.x;
    int gid = blockIdx.x * 256 + t;
    int val = (gid < N) ? deg[gid] : 0;
    tmp[t] = val;
    __syncthreads();
    for (int off = 1; off < 256; off <<= 1) {
        int add = (t >= off) ? tmp[t - off] : 0;
        __syncthreads();
        tmp[t] += add;
        __syncthreads();
    }
    int excl = tmp[t] - val + bsum[blockIdx.x];
    if (gid < N) { rowptr[gid] = excl; cursor[gid] = excl; }
    if (gid == N - 1) rowptr[N] = excl + val;
}

__global__ __launch_bounds__(256) void fill_csr_kernel(
    const int* __restrict__ esrc, const int* __restrict__ edst,
    int* __restrict__ cursor, int* __restrict__ csr_src, int E)
{
    int e = blockIdx.x * blockDim.x + threadIdx.x;
    if (e < E) {
        int pos = atomicAdd(&cursor[edst[e]], 1);
        csr_src[pos] = esrc[e];
    }
}

// ---------------------------------------------------------------------------
// weight transpose+cast: out[c][r] = bf16(in[r][c]); per-z-slice matrices
// ---------------------------------------------------------------------------
__global__ __launch_bounds__(256) void transpose_cast_kernel(
    const float* __restrict__ in, uint16_t* __restrict__ out,
    int R, int C, size_t inLS, size_t outLS)
{
    __shared__ float t[32][33];
    in  += blockIdx.z * inLS;
    out += blockIdx.z * outLS;
    int c0 = blockIdx.x * 32, r0 = blockIdx.y * 32;
    int tx = threadIdx.x, ty = threadIdx.y;  // (32,8)
    #pragma unroll
    for (int i = 0; i < 4; ++i)
        t[ty + i * 8][tx] = in[(size_t)(r0 + ty + i * 8) * C + c0 + tx];
    __syncthreads();
    #pragma unroll
    for (int i = 0; i < 4; ++i)
        out[(size_t)(c0 + ty + i * 8) * R + r0 + tx] = f2bf(t[tx][ty + i * 8]);
}

__global__ __launch_bounds__(256) void cast_f32_bf16_kernel(
    const float* __restrict__ in, uint16_t* __restrict__ out, int n4)
{
    int i = blockIdx.x * blockDim.x + threadIdx.x;
    if (i >= n4) return;
    float4 f = ((const float4*)in)[i];
    uint16_t o0 = f2bf(f.x), o1 = f2bf(f.y), o2 = f2bf(f.z), o3 = f2bf(f.w);
    uint2 pk;
    pk.x = (unsigned)o0 | ((unsigned)o1 << 16);
    pk.y = (unsigned)o2 | ((unsigned)o3 << 16);
    ((uint2*)out)[i] = pk;
}

__global__ __launch_bounds__(256) void build_qkv_bias_kernel(
    const float* __restrict__ bq, float* __restrict__ qb, int total)
{
    int i = blockIdx.x * blockDim.x + threadIdx.x;
    if (i >= total) return;
    int l = i / 768, c = i - l * 768;
    qb[i] = (c < 256) ? bq[l * 256 + c] : 0.f;
}

// ---------------------------------------------------------------------------
// bf16 MFMA GEMM, 128x256 tile, 256 threads / 4 waves.
// Each wave: 128 rows x 64-col slice -> 8x4 MFMA tiles (32 MFMA per K-step).
// grid.y = 256-col blocks. Staging: 6 x global_load_lds(16B) per thread.
// qkv_mode: blockIdx.y 0->q(bf16), 1->kb(bf16), 2->v8(fp8), each [M][256].
// std mode: Cstd[m*Nstd + col0 + n] bf16, optional relu.
// ---------------------------------------------------------------------------
__global__ __launch_bounds__(256, 2) void gemm128_kernel(
    const uint16_t* __restrict__ A, int lda, int M, int K,
    const uint16_t* __restrict__ BT,
    const float* __restrict__ bias,
    int qkv_mode,
    uint16_t* __restrict__ q, uint16_t* __restrict__ kb, uint8_t* __restrict__ v8,
    uint16_t* __restrict__ Cstd, int Nstd, int relu)
{
    __shared__ __align__(16) uint16_t As[128 * 32];   //  8 KB
    __shared__ __align__(16) uint16_t Bs[256 * 32];   // 16 KB

    const int tid  = threadIdx.x;
    const int lane = tid & 63;
    const int w    = tid >> 6;
    const int quad = lane >> 4;
    const int l15  = lane & 15;
    const int m0   = blockIdx.x * 128;
    const int col0 = blockIdx.y * 256;

    f32x4 acc[8][4] = {};

    const int r_a = tid >> 2;            // 0..63
    const int kc  = (tid & 3) * 8;       // k elem offset

    for (int k0 = 0; k0 < K; k0 += 32) {
        #pragma unroll
        for (int j = 0; j < 2; ++j) {
            int gr = m0 + j * 64 + r_a; if (gr > M - 1) gr = M - 1;
            gload_lds16(A + (size_t)gr * lda + k0 + kc, &As[(j * 256 + tid) * 8]);
        }
        #pragma unroll
        for (int j = 0; j < 4; ++j) {
            int n = j * 64 + r_a;
            gload_lds16(BT + (size_t)(col0 + n) * K + k0 + kc, &Bs[(j * 256 + tid) * 8]);
        }
        __syncthreads();

        s16x8 af[8], bf[4];
        #pragma unroll
        for (int i = 0; i < 8; ++i)
            af[i] = *(const s16x8*)&As[(i * 16 + l15) * 32 + quad * 8];
        #pragma unroll
        for (int jt = 0; jt < 4; ++jt)
            bf[jt] = *(const s16x8*)&Bs[(w * 64 + jt * 16 + l15) * 32 + quad * 8];
        #pragma unroll
        for (int i = 0; i < 8; ++i)
            #pragma unroll
            for (int jt = 0; jt < 4; ++jt)
                acc[i][jt] = __builtin_amdgcn_mfma_f32_16x16x32_bf16(
                    af[i], bf[jt], acc[i][jt], 0, 0, 0);
        __syncthreads();
    }

    float bv[4];
    #pragma unroll
    for (int jt = 0; jt < 4; ++jt)
        bv[jt] = bias[col0 + w * 64 + jt * 16 + l15];

    #pragma unroll
    for (int i = 0; i < 8; ++i) {
        #pragma unroll
        for (int r = 0; r < 4; ++r) {
            int m = m0 + i * 16 + quad * 4 + r;
            if (m >= M) continue;
            #pragma unroll
            for (int jt = 0; jt < 4; ++jt) {
                int nl = w * 64 + jt * 16 + l15;
                float val = acc[i][jt][r] + bv[jt];
                if (relu) val = fmaxf(val, 0.f);
                if (qkv_mode) {
                    if (blockIdx.y == 0)      q [(size_t)m * 256 + nl] = f2bf(val);
                    else if (blockIdx.y == 1) kb[(size_t)m * 256 + nl] = f2bf(val);
                    else                      v8[(size_t)m * 256 + nl] = f2fp8(val);
                } else {
                    Cstd[(size_t)m * Nstd + col0 + nl] = f2bf(val);
                }
            }
        }
    }
}

// ---------------------------------------------------------------------------
// bf16 MFMA GEMM + fused LayerNorm (Nc == 256 == one LN row per block-row).
// Tile 64Mx256N, 4 waves (each 64x64), BK=32, global_load_lds staging.
// ---------------------------------------------------------------------------
__global__ __launch_bounds__(256) void gemm_ln_kernel(
    const uint16_t* __restrict__ A, int lda, int M, int K,
    const uint16_t* __restrict__ BT,
    const float* __restrict__ bias,
    const float* __restrict__ resid,
    const float* __restrict__ g, const float* __restrict__ b,
    float* __restrict__ Cf, uint16_t* __restrict__ Cb)
{
    __shared__ __align__(16) uint16_t As[64 * 32];
    __shared__ __align__(16) uint16_t Bs[256 * 32];
    __shared__ float sS[64][4];
    __shared__ float sQ[64][4];

    const int tid  = threadIdx.x;
    const int lane = tid & 63;
    const int w    = tid >> 6;
    const int quad = lane >> 4;
    const int l15  = lane & 15;

    const int m0 = blockIdx.x * 64;

    f32x4 acc[4][4] = {};

    for (int k0 = 0; k0 < K; k0 += 32) {
        {
            int slot = tid;
            int r = slot >> 2, kc = (slot & 3) * 8;
            int gr = m0 + r; if (gr > M - 1) gr = M - 1;
            gload_lds16(A + (size_t)gr * lda + k0 + kc, &As[slot * 8]);
        }
        #pragma unroll
        for (int i = 0; i < 4; ++i) {
            int slot = i * 256 + tid;
            int n = slot >> 2, kc = (slot & 3) * 8;
            gload_lds16(BT + (size_t)n * K + k0 + kc, &Bs[slot * 8]);
        }
        __syncthreads();

        s16x8 af[4], bf[4];
        #pragma unroll
        for (int t = 0; t < 4; ++t) {
            af[t] = *(const s16x8*)&As[(t * 16 + l15) * 32 + quad * 8];
            bf[t] = *(const s16x8*)&Bs[(w * 64 + t * 16 + l15) * 32 + quad * 8];
        }
        #pragma unroll
        for (int i = 0; i < 4; ++i)
            #pragma unroll
            for (int jt = 0; jt < 4; ++jt)
                acc[i][jt] = __builtin_amdgcn_mfma_f32_16x16x32_bf16(
                    af[i], bf[jt], acc[i][jt], 0, 0, 0);
        __syncthreads();
    }

    float bv[4], gv[4], bbv[4];
    #pragma unroll
    for (int jt = 0; jt < 4; ++jt) {
        int n = w * 64 + jt * 16 + l15;
        bv[jt]  = bias[n];
        gv[jt]  = g[n];
        bbv[jt] = b[n];
    }

    #pragma unroll
    for (int i = 0; i < 4; ++i) {
        #pragma unroll
        for (int r = 0; r < 4; ++r) {
            int ml = i * 16 + quad * 4 + r;
            int m  = m0 + ml;
            bool valid = (m < M);
            float s = 0.f, s2 = 0.f;
            #pragma unroll
            for (int jt = 0; jt < 4; ++jt) {
                int n = w * 64 + jt * 16 + l15;
                float val = acc[i][jt][r] + bv[jt];
                if (valid) val += resid[(size_t)m * 256 + n];
                acc[i][jt][r] = val;
                s += val;
                s2 += val * val;
            }
            #pragma unroll
            for (int o = 1; o < 16; o <<= 1) {
                s  += __shfl_xor(s, o);
                s2 += __shfl_xor(s2, o);
            }
            if (l15 == 0) { sS[ml][w] = s; sQ[ml][w] = s2; }
        }
    }
    __syncthreads();

    #pragma unroll
    for (int i = 0; i < 4; ++i) {
        #pragma unroll
        for (int r = 0; r < 4; ++r) {
            int ml = i * 16 + quad * 4 + r;
            int m  = m0 + ml;
            if (m >= M) continue;
            float s  = sS[ml][0] + sS[ml][1] + sS[ml][2] + sS[ml][3];
            float s2 = sQ[ml][0] + sQ[ml][1] + sQ[ml][2] + sQ[ml][3];
            float mean = s * (1.f / 256.f);
            float var  = s2 * (1.f / 256.f) - mean * mean;
            float rstd = rsqrtf(var + 1e-5f);
            #pragma unroll
            for (int jt = 0; jt < 4; ++jt) {
                int n = w * 64 + jt * 16 + l15;
                float out = (acc[i][jt][r] - mean) * rstd * gv[jt] + bbv[jt];
                Cf[(size_t)m * 256 + n] = out;
                if (Cb) Cb[(size_t)m * 256 + n] = f2bf(out);
            }
        }
    }
}

// ---------------------------------------------------------------------------
// Fused per-node attention: one wave per dst node.
// q,kb bf16 [N][256]; v8 fp8-e4m3 [N][256]. ILP-2; fp32 accumulation;
// o written in-place over q (own-node only).
// ---------------------------------------------------------------------------
__global__ __launch_bounds__(256) void node_attn_kernel(
    uint16_t* __restrict__ q, const uint16_t* __restrict__ kb,
    const uint8_t* __restrict__ v8,
    const int* __restrict__ rowptr, const int* __restrict__ csr_src, int N)
{
    int node = (blockIdx.x * blockDim.x + threadIdx.x) >> 6;
    int lane = threadIdx.x & 63;
    if (node >= N) return;

    uint16_t* qp = q + (size_t)node * 256 + lane * 4;
    uint2 qu = *(const uint2*)qp;
    float q0 = bf2f((uint16_t)(qu.x & 0xFFFF)), q1 = bf2f((uint16_t)(qu.x >> 16));
    float q2 = bf2f((uint16_t)(qu.y & 0xFFFF)), q3 = bf2f((uint16_t)(qu.y >> 16));

    float a0 = 0.f, a1 = 0.f, a2 = 0.f, a3 = 0.f, zacc = 0.f;
    const float inv_sqrt_dk = 0.17677669529663687f;  // 1/sqrt(32)

    int beg = rowptr[node], end = rowptr[node + 1];
    int i = beg;
    for (; i + 1 < end; i += 2) {
        int s0 = csr_src[i], s1 = csr_src[i + 1];
        uint2 ku0 = *(const uint2*)(kb + (size_t)s0 * 256 + lane * 4);
        uint2 ku1 = *(const uint2*)(kb + (size_t)s1 * 256 + lane * 4);
        unsigned vu0 = *(const unsigned*)(v8 + (size_t)s0 * 256 + lane * 4);
        unsigned vu1 = *(const unsigned*)(v8 + (size_t)s1 * 256 + lane * 4);

        float p0 = bf2f((uint16_t)(ku0.x & 0xFFFF)) * q0
                 + bf2f((uint16_t)(ku0.x >> 16))   * q1
                 + bf2f((uint16_t)(ku0.y & 0xFFFF)) * q2
                 + bf2f((uint16_t)(ku0.y >> 16))   * q3;
        float p1 = bf2f((uint16_t)(ku1.x & 0xFFFF)) * q0
                 + bf2f((uint16_t)(ku1.x >> 16))   * q1
                 + bf2f((uint16_t)(ku1.y & 0xFFFF)) * q2
                 + bf2f((uint16_t)(ku1.y >> 16))   * q3;
        p0 += __shfl_xor(p0, 1); p1 += __shfl_xor(p1, 1);
        p0 += __shfl_xor(p0, 2); p1 += __shfl_xor(p1, 2);
        p0 += __shfl_xor(p0, 4); p1 += __shfl_xor(p1, 4);
        float sc0 = __expf(fminf(fmaxf(p0 * inv_sqrt_dk, -5.f), 5.f));
        float sc1 = __expf(fminf(fmaxf(p1 * inv_sqrt_dk, -5.f), 5.f));

        f32x2 vA0 = __builtin_amdgcn_cvt_pk_f32_fp8(vu0, false);
        f32x2 vB0 = __builtin_amdgcn_cvt_pk_f32_fp8(vu0, true);
        f32x2 vA1 = __builtin_amdgcn_cvt_pk_f32_fp8(vu1, false);
        f32x2 vB1 = __builtin_amdgcn_cvt_pk_f32_fp8(vu1, true);

        a0 += vA0[0] * sc0 + vA1[0] * sc1;
        a1 += vA0[1] * sc0 + vA1[1] * sc1;
        a2 += vB0[0] * sc0 + vB1[0] * sc1;
        a3 += vB0[1] * sc0 + vB1[1] * sc1;
        zacc += sc0 + sc1;
    }
    if (i < end) {
        int s = csr_src[i];
        uint2 ku = *(const uint2*)(kb + (size_t)s * 256 + lane * 4);
        unsigned vu = *(const unsigned*)(v8 + (size_t)s * 256 + lane * 4);
        float p = bf2f((uint16_t)(ku.x & 0xFFFF)) * q0
                + bf2f((uint16_t)(ku.x >> 16))   * q1
                + bf2f((uint16_t)(ku.y & 0xFFFF)) * q2
                + bf2f((uint16_t)(ku.y >> 16))   * q3;
        p += __shfl_xor(p, 1);
        p += __shfl_xor(p, 2);
        p += __shfl_xor(p, 4);
        float sc = __expf(fminf(fmaxf(p * inv_sqrt_dk, -5.f), 5.f));
        f32x2 vA = __builtin_amdgcn_cvt_pk_f32_fp8(vu, false);
        f32x2 vB = __builtin_amdgcn_cvt_pk_f32_fp8(vu, true);
        a0 += vA[0] * sc;
        a1 += vA[1] * sc;
        a2 += vB[0] * sc;
        a3 += vB[1] * sc;
        zacc += sc;
    }
    float inv = 1.f / zacc;
    uint2 pk;
    pk.x = (unsigned)f2bf(a0 * inv) | ((unsigned)f2bf(a1 * inv) << 16);
    pk.y = (unsigned)f2bf(a2 * inv) | ((unsigned)f2bf(a3 * inv) << 16);
    *(uint2*)qp = pk;
}

// ---------------------------------------------------------------------------
extern "C" void kernel_launch(void* const* d_in, const int* in_sizes, int n_in,
                              void* d_out, int out_size, void* d_ws, size_t ws_size,
                              hipStream_t stream)
{
    const float* x0   = (const float*)d_in[0];
    const int* esrc   = (const int*)d_in[1];
    const int* edst   = (const int*)d_in[2];
    const float* Wq   = (const float*)d_in[3];
    const float* bq   = (const float*)d_in[4];
    const float* Wk   = (const float*)d_in[5];
    const float* Wv   = (const float*)d_in[6];
    const float* Wo   = (const float*)d_in[7];
    const float* bo   = (const float*)d_in[8];
    const float* ln1g = (const float*)d_in[9];
    const float* ln1b = (const float*)d_in[10];
    const float* W1   = (const float*)d_in[11];
    const float* b1   = (const float*)d_in[12];
    const float* W2   = (const float*)d_in[13];
    const float* b2   = (const float*)d_in[14];
    const float* ln2g = (const float*)d_in[15];
    const float* ln2b = (const float*)d_in[16];

    const int N = in_sizes[0] / D;
    const int E = in_sizes[1];
    const int L = in_sizes[3] / (D * D);
    const size_t ND = (size_t)N * D;

    // ---- workspace layout (~237 MB) ----
    char* p = (char*)d_ws;
    float* bufX   = (float*)p;     p += ND * 4;   // fp32 residual stream
    uint16_t* xb  = (uint16_t*)p;  p += ND * 2;   // bf16 x (QKV A-input)
    uint16_t* q   = (uint16_t*)p;  p += ND * 2;   // bf16 q / o (in-place)
    uint16_t* kb  = (uint16_t*)p;  p += ND * 2;   // bf16 k
    uint8_t*  v8  = (uint8_t*)p;   p += ND;       // fp8 v
    p += ND * 3;                                  // extra so t1 fits
    uint16_t* t1  = q;   // [N][1024] bf16 = 8*ND bytes, spans q..extra
    uint16_t* hb  = (uint16_t*)p;  p += ND * 2;   // bf16 h (FF1 A-input)
    uint16_t* BTqkv = (uint16_t*)p; p += (size_t)L * 768 * 256 * 2;
    uint16_t* BTo   = (uint16_t*)p; p += (size_t)L * 256 * 256 * 2;
    uint16_t* BT1   = (uint16_t*)p; p += (size_t)L * 1024 * 256 * 2;
    uint16_t* BT2   = (uint16_t*)p; p += (size_t)L * 256 * 1024 * 2;
    float* qbias    = (float*)p;    p += (size_t)L * 768 * 4;
    int* rowptr  = (int*)p;         p += (size_t)(N + 1) * 4;
    int* cursor  = (int*)p;         p += (size_t)N * 4;
    int* deg     = cursor;
    int* csr_src = (int*)p;         p += (size_t)E * 4;
    int* bsum    = (int*)p;

    const int nb = cdiv(N, 256);
    dim3 blk(256);
    int edgeBlocks = cdiv(E, 256);
    int nodeBlocks = cdiv(N, 4);

    // ---- one-time setup ----
    dim3 tb(32, 8);
    transpose_cast_kernel<<<dim3(8, 8, L), tb, 0, stream>>>(Wq, BTqkv, 256, 256, (size_t)65536, (size_t)768 * 256);
    transpose_cast_kernel<<<dim3(8, 8, L), tb, 0, stream>>>(Wk, BTqkv + 256 * 256, 256, 256, (size_t)65536, (size_t)768 * 256);
    transpose_cast_kernel<<<dim3(8, 8, L), tb, 0, stream>>>(Wv, BTqkv + 512 * 256, 256, 256, (size_t)65536, (size_t)768 * 256);
    transpose_cast_kernel<<<dim3(8, 8, L), tb, 0, stream>>>(Wo, BTo, 256, 256, (size_t)65536, (size_t)65536);
    transpose_cast_kernel<<<dim3(32, 8, L), tb, 0, stream>>>(W1, BT1, 256, 1024, (size_t)262144, (size_t)262144);
    transpose_cast_kernel<<<dim3(8, 32, L), tb, 0, stream>>>(W2, BT2, 1024, 256, (size_t)262144, (size_t)262144);
    build_qkv_bias_kernel<<<cdiv(L * 768, 256), blk, 0, stream>>>(bq, qbias, L * 768);
    cast_f32_bf16_kernel<<<cdiv((int)(ND / 4), 256), blk, 0, stream>>>(x0, xb, (int)(ND / 4));

    zero_int_kernel<<<cdiv(N, 256), blk, 0, stream>>>(deg, N);
    count_deg_kernel<<<edgeBlocks, blk, 0, stream>>>(edst, deg, E);
    block_sum_kernel<<<nb, blk, 0, stream>>>(deg, bsum, N);
    scan_bsum_kernel<<<1, blk, 0, stream>>>(bsum, nb);
    scan_write_kernel<<<nb, blk, 0, stream>>>(deg, bsum, rowptr, cursor, N);
    fill_csr_kernel<<<edgeBlocks, blk, 0, stream>>>(esrc, edst, cursor, csr_src, E);

    const int Mt128 = cdiv(N, 128);
    const int Mt64  = cdiv(N, 64);
    dim3 gQKV(Mt128, 3);
    dim3 gF1(Mt128, 4);
    dim3 gLN(Mt64, 1);

    for (int l = 0; l < L; ++l) {
        const uint16_t* BTqkv_l = BTqkv + (size_t)l * 768 * 256;
        const uint16_t* BTo_l   = BTo + (size_t)l * 65536;
        const uint16_t* BT1_l   = BT1 + (size_t)l * 262144;
        const uint16_t* BT2_l   = BT2 + (size_t)l * 262144;
        const float* xin_f = (l == 0) ? x0 : bufX;

        // q,k (bf16) + v (fp8) = xb @ [Wq|Wk|Wv] + [bq|0|0]
        gemm128_kernel<<<gQKV, blk, 0, stream>>>(xb, 256, N, 256, BTqkv_l,
            qbias + (size_t)l * 768, 1, q, kb, v8, nullptr, 0, 0);

        // o (over q) = softmax-weighted aggregate
        node_attn_kernel<<<nodeBlocks, blk, 0, stream>>>(q, kb, v8, rowptr, csr_src, N);

        // bufX = LN1(xin + o@Wo + bo)  -> fp32 bufX + bf16 hb
        gemm_ln_kernel<<<gLN, blk, 0, stream>>>(q, 256, N, 256, BTo_l,
            bo + (size_t)l * 256, xin_f, ln1g + (size_t)l * 256, ln1b + (size_t)l * 256,
            bufX, hb);

        // t1 = relu(h@W1 + b1) (bf16)
        gemm128_kernel<<<gF1, blk, 0, stream>>>(hb, 256, N, 256, BT1_l,
            b1 + (size_t)l * 1024, 0, nullptr, nullptr, nullptr, t1, 1024, 1);

        // fout = LN2(h + t1@W2 + b2)  -> fp32 fout + bf16 xb
        float* fout = (l == L - 1) ? (float*)d_out : bufX;
        gemm_ln_kernel<<<gLN, blk, 0, stream>>>(t1, 1024, N, 1024, BT2_l,
            b2 + (size_t)l * 256, bufX, ln2g + (size_t)l * 256, ln2b + (size_t)l * 256,
            fout, (l == L - 1) ? nullptr : xb);
    }
}